// Round 1
// baseline (1476.233 us; speedup 1.0000x reference)
//
#include <hip/hip_runtime.h>
#include <hip/hip_bf16.h>

#define NN      150000
#define NUSERS  50000
#define DD      128
#define EE      500000
#define BB      16384

// ---------------- degree / norm ----------------
__global__ __launch_bounds__(256) void count_k(const int* __restrict__ dst,
                                               float* __restrict__ deg) {
    int e = blockIdx.x * 256 + threadIdx.x;
    if (e < EE) atomicAdd(&deg[dst[e]], 1.0f);
}

__global__ __launch_bounds__(256) void dis_k(float* __restrict__ deg) {
    int i = blockIdx.x * 256 + threadIdx.x;
    if (i < NN) deg[i] = rsqrtf(deg[i] + 1.0f);
}

__global__ __launch_bounds__(256) void norm_k(const int* __restrict__ src,
                                              const int* __restrict__ dst,
                                              const float* __restrict__ dis,
                                              float* __restrict__ nrm) {
    int e = blockIdx.x * 256 + threadIdx.x;
    if (e < EE) nrm[e] = dis[src[e]] * dis[dst[e]];
}

// ---------------- W transpose (Wt[c][k] = W[k][c]) so GEMM can float4 along k
__global__ __launch_bounds__(256) void wt_k(const float* __restrict__ W1,
                                            const float* __restrict__ W2,
                                            float* __restrict__ Wt1,
                                            float* __restrict__ Wt2) {
    int idx = blockIdx.x * 256 + threadIdx.x;   // [0, 32768)
    int m = idx >> 14;
    int j = idx & 16383;
    int k = j >> 7, c = j & 127;
    if (m) Wt2[c * DD + k] = W2[j];
    else   Wt1[c * DD + k] = W1[j];
}

// ---------------- GEMM: out[r][c] = sum_k A[r][k] * W[k][c]  (Wt is [c][k])
// Block: 256 threads, 16 rows/block. Thread: col = tid&127, rowgroup = tid>>7,
// computes 8 rows (stride 2). A-row loads are wave-uniform (broadcast).
__global__ __launch_bounds__(256) void gemm_k(const float* __restrict__ A0,
                                              const float* __restrict__ A1,
                                              int nsplit,
                                              const float* __restrict__ Wt,
                                              float* __restrict__ out) {
    int r0 = blockIdx.x * 16;
    int c  = threadIdx.x & 127;
    int rg = threadIdx.x >> 7;
    const float* wrow = Wt + c * DD;

    const float* arow[8];
    float acc[8];
#pragma unroll
    for (int i = 0; i < 8; ++i) {
        int r = r0 + rg + 2 * i;
        arow[i] = (r < nsplit) ? (A0 + (size_t)r * DD)
                               : (A1 + (size_t)(r - nsplit) * DD);
        acc[i] = 0.f;
    }
#pragma unroll 4
    for (int k = 0; k < DD; k += 4) {
        float4 w = *(const float4*)(wrow + k);
#pragma unroll
        for (int i = 0; i < 8; ++i) {
            float4 a = *(const float4*)(arow[i] + k);
            acc[i] += a.x * w.x + a.y * w.y + a.z * w.z + a.w * w.w;
        }
    }
#pragma unroll
    for (int i = 0; i < 8; ++i) {
        int r = r0 + rg + 2 * i;
        out[(size_t)r * DD + c] = acc[i];
    }
}

// ---------------- self-loop init: agg[i][:] = h[i][:] * dis[i]^2  (float4)
__global__ __launch_bounds__(256) void selfinit_k(const float* __restrict__ h,
                                                  const float* __restrict__ dis,
                                                  float* __restrict__ agg) {
    int gid = blockIdx.x * 256 + threadIdx.x;     // N*32 float4 units
    if (gid >= NN * 32) return;
    int row = gid >> 5;
    float d = dis[row];
    float w = d * d;
    float4 v = ((const float4*)h)[gid];
    v.x *= w; v.y *= w; v.z *= w; v.w *= w;
    ((float4*)agg)[gid] = v;
}

// ---------------- edge scatter: agg[dst] += h[src] * norm  (fp32 atomics)
__global__ __launch_bounds__(256) void scatter_k(const float* __restrict__ h,
                                                 const int* __restrict__ src,
                                                 const int* __restrict__ dst,
                                                 const float* __restrict__ nrm,
                                                 float* __restrict__ agg) {
    int gid = blockIdx.x * 256 + threadIdx.x;     // E*128 threads
    int e = gid >> 7;
    int f = gid & 127;
    if (e < EE) {
        float v = h[(size_t)src[e] * DD + f] * nrm[e];
        atomicAdd(&agg[(size_t)dst[e] * DD + f], v);
    }
}

// ---------------- BN stats: per-column sum & sumsq
__global__ __launch_bounds__(256) void bnstats_k(const float* __restrict__ x,
                                                 float* __restrict__ sums) {
    int c  = threadIdx.x & 127;
    int rg = threadIdx.x >> 7;
    float s = 0.f, s2 = 0.f;
    int stride = gridDim.x * 2;
    for (int r = blockIdx.x * 2 + rg; r < NN; r += stride) {
        float v = x[(size_t)r * DD + c];
        s += v; s2 += v * v;
    }
    __shared__ float ls[256], ls2[256];
    ls[threadIdx.x] = s; ls2[threadIdx.x] = s2;
    __syncthreads();
    if (rg == 0) {
        s  = ls[c]  + ls[c + 128];
        s2 = ls2[c] + ls2[c + 128];
        atomicAdd(&sums[c], s);
        atomicAdd(&sums[128 + c], s2);
    }
}

// ---------------- BN coefficients: f(x) = x*scale + shift, then relu
__global__ void bncoef_k(const float* __restrict__ sums,
                         const float* __restrict__ gamma,
                         const float* __restrict__ beta,
                         float* __restrict__ coefs) {
    int c = threadIdx.x;
    if (c >= DD) return;
    const float n = (float)NN;
    float m  = sums[c] / n;
    float v  = sums[128 + c] / n - m * m;
    float is = rsqrtf(v + 1e-5f);
    float sc = gamma[c] * is;
    coefs[c] = sc;
    coefs[128 + c] = beta[c] - m * sc;
}

// ---------------- elementwise BN+relu: out = relu(in*scale+shift)  (float4)
__global__ __launch_bounds__(256) void transform_k(const float* __restrict__ in,
                                                   const float* __restrict__ coefs,
                                                   float* __restrict__ out) {
    int gid = blockIdx.x * 256 + threadIdx.x;     // N*32 float4 units
    if (gid >= NN * 32) return;
    int c4 = (gid & 31) * 4;
    float4 v  = ((const float4*)in)[gid];
    float4 sc = *(const float4*)(coefs + c4);
    float4 sh = *(const float4*)(coefs + 128 + c4);
    v.x = fmaxf(v.x * sc.x + sh.x, 0.f);
    v.y = fmaxf(v.y * sc.y + sh.y, 0.f);
    v.z = fmaxf(v.z * sc.z + sh.z, 0.f);
    v.w = fmaxf(v.w * sc.w + sh.w, 0.f);
    ((float4*)out)[gid] = v;
}

// ---------------- ratings: wave per pair, BN2+relu applied inline
__global__ __launch_bounds__(256) void ratings_k(const float* __restrict__ x,
                                                 const int* __restrict__ srcn,
                                                 const int* __restrict__ dstn,
                                                 const float* __restrict__ coefs,
                                                 float* __restrict__ out) {
    int wid  = (blockIdx.x * 256 + threadIdx.x) >> 6;
    int lane = threadIdx.x & 63;
    if (wid >= BB) return;
    int u = srcn[wid], v = dstn[wid];
    const float* xu = x + (size_t)u * DD;
    const float* xv = x + (size_t)v * DD;
    float acc = 0.f;
#pragma unroll
    for (int d0 = 0; d0 < DD; d0 += 64) {
        int d = d0 + lane;
        float sc = coefs[d], sh = coefs[128 + d];
        float a = fmaxf(xu[d] * sc + sh, 0.f);
        float b = fmaxf(xv[d] * sc + sh, 0.f);
        acc += a * b;
    }
#pragma unroll
    for (int off = 32; off; off >>= 1) acc += __shfl_down(acc, off, 64);
    if (lane == 0) out[wid] = acc;
}

extern "C" void kernel_launch(void* const* d_in, const int* in_sizes, int n_in,
                              void* d_out, int out_size, void* d_ws, size_t ws_size,
                              hipStream_t stream) {
    const int*   edge  = (const int*)d_in[0];      // [2,E]
    const int*   esrc  = edge;
    const int*   edst  = edge + EE;
    const int*   srcn  = (const int*)d_in[2];
    const int*   dstn  = (const int*)d_in[3];
    const float* uemb  = (const float*)d_in[4];
    const float* bemb  = (const float*)d_in[5];
    const float* W1    = (const float*)d_in[6];
    // b1 = d_in[7]  (cancels in BN — per-column constant)
    const float* g1    = (const float*)d_in[8];
    const float* be1   = (const float*)d_in[9];
    const float* W2    = (const float*)d_in[10];
    // b2 = d_in[11] (cancels in BN)
    const float* g2    = (const float*)d_in[12];
    const float* be2   = (const float*)d_in[13];
    float* out = (float*)d_out;

    // workspace layout (floats)
    float* bufA  = (float*)d_ws;                   // N*D
    float* bufB  = bufA + (size_t)NN * DD;         // N*D
    float* dis   = bufB + (size_t)NN * DD;         // N (holds deg first)
    float* nrm   = dis + 150016;                   // E
    float* Wt1   = nrm + EE;                       // 16384
    float* Wt2   = Wt1 + 16384;                    // 16384
    float* sums  = Wt2 + 16384;                    // 256
    float* coef1 = sums + 256;                     // 256
    float* coef2 = coef1 + 256;                    // 256

    const int egrid  = (EE + 255) / 256;
    const int ngrid  = (NN + 255) / 256;
    const int ewgrid = (EE * 128) / 256;           // 250000
    const int vgrid  = (NN * 32 + 255) / 256;      // float4 grids

    // degree / normalization
    hipMemsetAsync(dis, 0, (size_t)NN * sizeof(float), stream);
    count_k<<<egrid, 256, 0, stream>>>(edst, dis);
    dis_k<<<ngrid, 256, 0, stream>>>(dis);
    norm_k<<<egrid, 256, 0, stream>>>(esrc, edst, dis, nrm);
    wt_k<<<128, 256, 0, stream>>>(W1, W2, Wt1, Wt2);

    // ---- layer 1 ----
    gemm_k<<<NN / 16, 256, 0, stream>>>(uemb, bemb, NUSERS, Wt1, bufA);   // h1
    selfinit_k<<<vgrid, 256, 0, stream>>>(bufA, dis, bufB);               // agg1 init
    scatter_k<<<ewgrid, 256, 0, stream>>>(bufA, esrc, edst, nrm, bufB);   // agg1 += edges
    hipMemsetAsync(sums, 0, 256 * sizeof(float), stream);
    bnstats_k<<<512, 256, 0, stream>>>(bufB, sums);
    bncoef_k<<<1, 128, 0, stream>>>(sums, g1, be1, coef1);
    transform_k<<<vgrid, 256, 0, stream>>>(bufB, coef1, bufA);            // relu(bn1)

    // ---- layer 2 ----
    gemm_k<<<NN / 16, 256, 0, stream>>>(bufA, bufA, NN, Wt2, bufB);       // h2
    selfinit_k<<<vgrid, 256, 0, stream>>>(bufB, dis, bufA);               // agg2 init
    scatter_k<<<ewgrid, 256, 0, stream>>>(bufB, esrc, edst, nrm, bufA);   // agg2 += edges
    hipMemsetAsync(sums, 0, 256 * sizeof(float), stream);
    bnstats_k<<<512, 256, 0, stream>>>(bufA, sums);
    bncoef_k<<<1, 128, 0, stream>>>(sums, g2, be2, coef2);

    // ---- ratings (BN2+relu inline) ----
    ratings_k<<<BB / 4, 256, 0, stream>>>(bufA, srcn, dstn, coef2, out);
}

// Round 2
// 656.002 us; speedup vs baseline: 2.2503x; 2.2503x over previous
//
#include <hip/hip_runtime.h>
#include <hip/hip_bf16.h>

#define NN      150000
#define NUSERS  50000
#define DD      128
#define EE      500000
#define BB      16384

using short8 = __attribute__((ext_vector_type(8))) short;
using f32x4  = __attribute__((ext_vector_type(4))) float;

__device__ __forceinline__ short f2bf(float v) {
    unsigned u = __float_as_uint(v);
    u = (u + 0x7FFF + ((u >> 16) & 1)) >> 16;   // RNE
    return (short)u;
}
__device__ __forceinline__ float bf2f(unsigned short b) {
    return __uint_as_float(((unsigned)b) << 16);
}

// ---------------- degree / norm ----------------
__global__ __launch_bounds__(256) void count_k(const int* __restrict__ dst,
                                               float* __restrict__ deg) {
    int e = blockIdx.x * 256 + threadIdx.x;
    if (e < EE) atomicAdd(&deg[dst[e]], 1.0f);
}

__global__ __launch_bounds__(256) void dis_k(float* __restrict__ deg) {
    int i = blockIdx.x * 256 + threadIdx.x;
    if (i < NN) deg[i] = rsqrtf(deg[i] + 1.0f);
}

__global__ __launch_bounds__(256) void norm_k(const int* __restrict__ src,
                                              const int* __restrict__ dst,
                                              const float* __restrict__ dis,
                                              float* __restrict__ nrm) {
    int e = blockIdx.x * 256 + threadIdx.x;
    if (e < EE) nrm[e] = dis[src[e]] * dis[dst[e]];
}

// ---------------- Wfrag prep: per-lane MFMA B-fragments, bf16 ----------------
// Layout: F[((ct*4 + kk)*64 + lane)*8 + e] = W[kk*32 + (lane>>4)*8 + e][ct*16 + (lane&15)]
__global__ __launch_bounds__(256) void wfrag_k(const float* __restrict__ W1,
                                               const float* __restrict__ W2,
                                               short* __restrict__ F1,
                                               short* __restrict__ F2) {
    int idx = blockIdx.x * 256 + threadIdx.x;   // [0, 32768)
    int m = idx >> 14;
    int i = idx & 16383;
    int e  = i & 7;
    int l  = (i >> 3) & 63;
    int kk = (i >> 9) & 3;
    int ct = i >> 11;
    int k = kk * 32 + (l >> 4) * 8 + e;
    int c = ct * 16 + (l & 15);
    const float* W = m ? W2 : W1;
    short*       F = m ? F2 : F1;
    F[i] = f2bf(W[k * DD + c]);
}

// ---------------- MFMA GEMM, fused epilogue ----------------
// MODE 0: A = concat(A0[0:nsplit], A1) fp32, raw.   Layer 1.
// MODE 1: A = relu(A0 * coefs[c] + coefs[128+c]) fp32, in-place agg. Layer 2.
// Writes: hout (bf16) = A@W ; agg (fp32) = (A@W) * dis[row]^2
// Wave = 16 rows x 128 cols: 8 col-tiles x 4 k-steps of mfma_f32_16x16x32_bf16.
template<int MODE>
__global__ __launch_bounds__(256) void gemm_mfma_k(const float* __restrict__ A0,
                                                   const float* __restrict__ A1,
                                                   int nsplit,
                                                   const float* __restrict__ coefs,
                                                   const short* __restrict__ Wfrag,
                                                   const float* __restrict__ dis,
                                                   unsigned short* __restrict__ hout,
                                                   float* __restrict__ agg) {
    int wave = threadIdx.x >> 6;
    int lane = threadIdx.x & 63;
    int r0 = blockIdx.x * 64 + wave * 16;

    // A-fragment source row for this lane (clamped; tail stores are guarded)
    int lr = r0 + (lane & 15);
    if (lr > NN - 1) lr = NN - 1;
    const float* arow;
    if (MODE == 0) arow = (lr < nsplit) ? A0 + (size_t)lr * DD
                                        : A1 + (size_t)(lr - nsplit) * DD;
    else           arow = A0 + (size_t)lr * DD;

    int kgrp = lane >> 4;   // 0..3

    f32x4 acc[8];
#pragma unroll
    for (int ct = 0; ct < 8; ++ct) acc[ct] = (f32x4){0.f, 0.f, 0.f, 0.f};

#pragma unroll
    for (int kk = 0; kk < 4; ++kk) {
        int d0 = kk * 32 + kgrp * 8;
        f32x4 va = *(const f32x4*)(arow + d0);
        f32x4 vb = *(const f32x4*)(arow + d0 + 4);
        if (MODE == 1) {
            f32x4 s1 = *(const f32x4*)(coefs + d0);
            f32x4 s2 = *(const f32x4*)(coefs + d0 + 4);
            f32x4 t1 = *(const f32x4*)(coefs + 128 + d0);
            f32x4 t2 = *(const f32x4*)(coefs + 128 + d0 + 4);
#pragma unroll
            for (int j = 0; j < 4; ++j) {
                va[j] = fmaxf(va[j] * s1[j] + t1[j], 0.f);
                vb[j] = fmaxf(vb[j] * s2[j] + t2[j], 0.f);
            }
        }
        short8 afrag;
#pragma unroll
        for (int j = 0; j < 4; ++j) { afrag[j] = f2bf(va[j]); afrag[4 + j] = f2bf(vb[j]); }

        const short8* wf = (const short8*)Wfrag;
#pragma unroll
        for (int ct = 0; ct < 8; ++ct) {
            short8 wfr = wf[(ct * 4 + kk) * 64 + lane];
            acc[ct] = __builtin_amdgcn_mfma_f32_16x16x32_bf16(afrag, wfr, acc[ct], 0, 0, 0);
        }
    }

    // epilogue: C/D layout col = lane&15, row = (lane>>4)*4 + j   [m89-verified]
    int orow = r0 + kgrp * 4;
    float d2[4];
#pragma unroll
    for (int j = 0; j < 4; ++j) {
        int gr = orow + j;
        float dv = (gr < NN) ? dis[gr] : 0.f;
        d2[j] = dv * dv;
    }
#pragma unroll
    for (int ct = 0; ct < 8; ++ct) {
        int col = ct * 16 + (lane & 15);
#pragma unroll
        for (int j = 0; j < 4; ++j) {
            int gr = orow + j;
            if (gr < NN) {
                float v = acc[ct][j];
                hout[(size_t)gr * DD + col] = (unsigned short)f2bf(v);
                agg[(size_t)gr * DD + col]  = v * d2[j];
            }
        }
    }
}

// ---------------- edge scatter: agg[dst] += h[src] * norm  (bf16 gather) ----
__global__ __launch_bounds__(256) void scatter_k(const unsigned short* __restrict__ h,
                                                 const int* __restrict__ src,
                                                 const int* __restrict__ dst,
                                                 const float* __restrict__ nrm,
                                                 float* __restrict__ agg) {
    int gid = blockIdx.x * 256 + threadIdx.x;     // E*128 threads
    int e = gid >> 7;
    int f = gid & 127;
    if (e < EE) {
        float v = bf2f(h[(size_t)src[e] * DD + f]) * nrm[e];
        atomicAdd(&agg[(size_t)dst[e] * DD + f], v);
    }
}

// ---------------- BN stats: per-column sum & sumsq ----------------
__global__ __launch_bounds__(256) void bnstats_k(const float* __restrict__ x,
                                                 float* __restrict__ sums) {
    int c  = threadIdx.x & 127;
    int rg = threadIdx.x >> 7;
    float s = 0.f, s2 = 0.f;
    int stride = gridDim.x * 2;
    for (int r = blockIdx.x * 2 + rg; r < NN; r += stride) {
        float v = x[(size_t)r * DD + c];
        s += v; s2 += v * v;
    }
    __shared__ float ls[256], ls2[256];
    ls[threadIdx.x] = s; ls2[threadIdx.x] = s2;
    __syncthreads();
    if (rg == 0) {
        s  = ls[c]  + ls[c + 128];
        s2 = ls2[c] + ls2[c + 128];
        atomicAdd(&sums[c], s);
        atomicAdd(&sums[128 + c], s2);
    }
}

// ---------------- BN coefficients: f(x) = x*scale + shift ----------------
__global__ void bncoef_k(const float* __restrict__ sums,
                         const float* __restrict__ gamma,
                         const float* __restrict__ beta,
                         float* __restrict__ coefs) {
    int c = threadIdx.x;
    if (c >= DD) return;
    const float n = (float)NN;
    float m  = sums[c] / n;
    float v  = sums[128 + c] / n - m * m;
    float is = rsqrtf(v + 1e-5f);
    float sc = gamma[c] * is;
    coefs[c] = sc;
    coefs[128 + c] = beta[c] - m * sc;
}

// ---------------- ratings: wave per pair, BN2+relu applied inline ----------
__global__ __launch_bounds__(256) void ratings_k(const float* __restrict__ x,
                                                 const int* __restrict__ srcn,
                                                 const int* __restrict__ dstn,
                                                 const float* __restrict__ coefs,
                                                 float* __restrict__ out) {
    int wid  = (blockIdx.x * 256 + threadIdx.x) >> 6;
    int lane = threadIdx.x & 63;
    if (wid >= BB) return;
    int u = srcn[wid], v = dstn[wid];
    const float* xu = x + (size_t)u * DD;
    const float* xv = x + (size_t)v * DD;
    float acc = 0.f;
#pragma unroll
    for (int d0 = 0; d0 < DD; d0 += 64) {
        int d = d0 + lane;
        float sc = coefs[d], sh = coefs[128 + d];
        float a = fmaxf(xu[d] * sc + sh, 0.f);
        float b = fmaxf(xv[d] * sc + sh, 0.f);
        acc += a * b;
    }
#pragma unroll
    for (int off = 32; off; off >>= 1) acc += __shfl_down(acc, off, 64);
    if (lane == 0) out[wid] = acc;
}

extern "C" void kernel_launch(void* const* d_in, const int* in_sizes, int n_in,
                              void* d_out, int out_size, void* d_ws, size_t ws_size,
                              hipStream_t stream) {
    const int*   edge  = (const int*)d_in[0];      // [2,E]
    const int*   esrc  = edge;
    const int*   edst  = edge + EE;
    const int*   srcn  = (const int*)d_in[2];
    const int*   dstn  = (const int*)d_in[3];
    const float* uemb  = (const float*)d_in[4];
    const float* bemb  = (const float*)d_in[5];
    const float* W1    = (const float*)d_in[6];
    // b1 = d_in[7]  (per-column constant, cancels in BN)
    const float* g1    = (const float*)d_in[8];
    const float* be1   = (const float*)d_in[9];
    const float* W2    = (const float*)d_in[10];
    // b2 = d_in[11] (cancels in BN)
    const float* g2    = (const float*)d_in[12];
    const float* be2   = (const float*)d_in[13];
    float* out = (float*)d_out;

    // workspace layout (floats; all segments 16B-aligned)
    float*          agg   = (float*)d_ws;                       // N*D fp32 (layer1, reused in-place for layer2)
    unsigned short* hbuf  = (unsigned short*)(agg + (size_t)NN * DD);  // N*D bf16
    float*          dis   = (float*)(hbuf + (size_t)NN * DD);   // N (holds deg first)
    float*          nrm   = dis + 150016;                       // E
    short*          Wf1   = (short*)(nrm + EE);                 // 16384 bf16
    short*          Wf2   = Wf1 + 16384;                        // 16384 bf16
    float*          sums  = (float*)(Wf2 + 16384);              // 256
    float*          coef1 = sums + 256;                         // 256
    float*          coef2 = coef1 + 256;                        // 256

    const int egrid  = (EE + 255) / 256;
    const int ngrid  = (NN + 255) / 256;
    const int ewgrid = (EE * 128) / 256;           // 250000
    const int ggrid  = (NN + 63) / 64;             // 2344 MFMA-GEMM blocks

    // degree / normalization / W fragments
    hipMemsetAsync(dis, 0, (size_t)NN * sizeof(float), stream);
    count_k<<<egrid, 256, 0, stream>>>(edst, dis);
    dis_k<<<ngrid, 256, 0, stream>>>(dis);
    norm_k<<<egrid, 256, 0, stream>>>(esrc, edst, dis, nrm);
    wfrag_k<<<128, 256, 0, stream>>>(W1, W2, Wf1, Wf2);

    // ---- layer 1: h1 = X@W1 (bf16) ; agg = h1*dis^2 ; scatter ; BN stats ----
    gemm_mfma_k<0><<<ggrid, 256, 0, stream>>>(uemb, bemb, NUSERS, nullptr, Wf1, dis, hbuf, agg);
    scatter_k<<<ewgrid, 256, 0, stream>>>(hbuf, esrc, edst, nrm, agg);
    hipMemsetAsync(sums, 0, 256 * sizeof(float), stream);
    bnstats_k<<<512, 256, 0, stream>>>(agg, sums);
    bncoef_k<<<1, 128, 0, stream>>>(sums, g1, be1, coef1);

    // ---- layer 2: x1 = relu(bn1(agg)) fused into A-load; in-place agg ----
    gemm_mfma_k<1><<<ggrid, 256, 0, stream>>>(agg, nullptr, 0, coef1, Wf2, dis, hbuf, agg);
    scatter_k<<<ewgrid, 256, 0, stream>>>(hbuf, esrc, edst, nrm, agg);
    hipMemsetAsync(sums, 0, 256 * sizeof(float), stream);
    bnstats_k<<<512, 256, 0, stream>>>(agg, sums);
    bncoef_k<<<1, 128, 0, stream>>>(sums, g2, be2, coef2);

    // ---- ratings (BN2+relu inline) ----
    ratings_k<<<BB / 4, 256, 0, stream>>>(agg, srcn, dstn, coef2, out);
}

// Round 3
// 379.262 us; speedup vs baseline: 3.8924x; 1.7297x over previous
//
#include <hip/hip_runtime.h>
#include <hip/hip_bf16.h>

#define NN      150000
#define NUSERS  50000
#define DD      128
#define EE      500000
#define BB      16384
#define NBLK    586          // ceil(NN/256)

using short8 = __attribute__((ext_vector_type(8))) short;
using f32x4  = __attribute__((ext_vector_type(4))) float;

__device__ __forceinline__ short f2bf(float v) {
    unsigned u = __float_as_uint(v);
    u = (u + 0x7FFF + ((u >> 16) & 1)) >> 16;   // RNE
    return (short)u;
}
__device__ __forceinline__ float bf2f(unsigned short b) {
    return __uint_as_float(((unsigned)b) << 16);
}

// ---------------- degree count (int) ----------------
__global__ __launch_bounds__(256) void count_k(const int* __restrict__ dst,
                                               int* __restrict__ cnt) {
    int e = blockIdx.x * 256 + threadIdx.x;
    if (e < EE) atomicAdd(&cnt[dst[e]], 1);
}

// ---------------- hierarchical exclusive scan of cnt -> rowptr ----------------
__global__ __launch_bounds__(256) void scan1_k(const int* __restrict__ cnt,
                                               int* __restrict__ rowptr,
                                               int* __restrict__ bsum) {
    __shared__ int s[256];
    int t = threadIdx.x;
    int i = blockIdx.x * 256 + t;
    int v = (i < NN) ? cnt[i] : 0;
    s[t] = v; __syncthreads();
    for (int off = 1; off < 256; off <<= 1) {
        int x = (t >= off) ? s[t - off] : 0;
        __syncthreads();
        s[t] += x;
        __syncthreads();
    }
    if (i < NN) rowptr[i] = s[t] - v;           // block-local exclusive
    if (t == 255) bsum[blockIdx.x] = s[255];
}

__global__ __launch_bounds__(1024) void scan2_k(int* __restrict__ bsum) {
    __shared__ int s[1024];
    int t = threadIdx.x;
    int v = (t < NBLK) ? bsum[t] : 0;
    s[t] = v; __syncthreads();
    for (int off = 1; off < 1024; off <<= 1) {
        int x = (t >= off) ? s[t - off] : 0;
        __syncthreads();
        s[t] += x;
        __syncthreads();
    }
    if (t < NBLK) bsum[t] = s[t] - v;           // exclusive block offsets
}

__global__ __launch_bounds__(256) void scan3_k(int* __restrict__ rowptr,
                                               const int* __restrict__ bsum,
                                               int* __restrict__ cur) {
    int i = blockIdx.x * 256 + threadIdx.x;
    if (i < NN) {
        int v = rowptr[i] + bsum[blockIdx.x];
        rowptr[i] = v;
        cur[i] = v;
    }
    if (i == 0) rowptr[NN] = EE;
}

// ---------------- dis = rsqrt(deg+1) ----------------
__global__ __launch_bounds__(256) void dis_k(const int* __restrict__ cnt,
                                             float* __restrict__ dis) {
    int i = blockIdx.x * 256 + threadIdx.x;
    if (i < NN) dis[i] = rsqrtf((float)cnt[i] + 1.0f);
}

// ---------------- CSR fill (counting sort by dst) ----------------
__global__ __launch_bounds__(256) void fill_k(const int* __restrict__ src,
                                              const int* __restrict__ dst,
                                              const float* __restrict__ dis,
                                              int* __restrict__ cur,
                                              int* __restrict__ ssrc,
                                              float* __restrict__ ssdis) {
    int e = blockIdx.x * 256 + threadIdx.x;
    if (e < EE) {
        int d = dst[e], s = src[e];
        int pos = atomicAdd(&cur[d], 1);
        ssrc[pos]  = s;
        ssdis[pos] = dis[s];
    }
}

// ---------------- Wfrag prep: per-lane MFMA B-fragments, bf16 ----------------
// F[((ct*4 + kk)*64 + lane)*8 + e] = W[kk*32 + (lane>>4)*8 + e][ct*16 + (lane&15)]
__global__ __launch_bounds__(256) void wfrag_k(const float* __restrict__ W1,
                                               const float* __restrict__ W2,
                                               short* __restrict__ F1,
                                               short* __restrict__ F2) {
    int idx = blockIdx.x * 256 + threadIdx.x;   // [0, 32768)
    int m = idx >> 14;
    int i = idx & 16383;
    int e  = i & 7;
    int l  = (i >> 3) & 63;
    int kk = (i >> 9) & 3;
    int ct = i >> 11;
    int k = kk * 32 + (l >> 4) * 8 + e;
    int c = ct * 16 + (l & 15);
    const float* W = m ? W2 : W1;
    short*       F = m ? F2 : F1;
    F[i] = f2bf(W[k * DD + c]);
}

// ---------------- MFMA GEMM: hout(bf16) = A @ W ----------------
// MODE 0: A = concat(A0[0:nsplit], A1) fp32, raw.   Layer 1.
// MODE 1: A = relu(A0 * coefs[c] + coefs[128+c]).   Layer 2.
template<int MODE>
__global__ __launch_bounds__(256) void gemm_mfma_k(const float* __restrict__ A0,
                                                   const float* __restrict__ A1,
                                                   int nsplit,
                                                   const float* __restrict__ coefs,
                                                   const short* __restrict__ Wfrag,
                                                   unsigned short* __restrict__ hout) {
    int wave = threadIdx.x >> 6;
    int lane = threadIdx.x & 63;
    int r0 = blockIdx.x * 64 + wave * 16;

    int lr = r0 + (lane & 15);
    if (lr > NN - 1) lr = NN - 1;
    const float* arow;
    if (MODE == 0) arow = (lr < nsplit) ? A0 + (size_t)lr * DD
                                        : A1 + (size_t)(lr - nsplit) * DD;
    else           arow = A0 + (size_t)lr * DD;

    int kgrp = lane >> 4;   // 0..3

    f32x4 acc[8];
#pragma unroll
    for (int ct = 0; ct < 8; ++ct) acc[ct] = (f32x4){0.f, 0.f, 0.f, 0.f};

#pragma unroll
    for (int kk = 0; kk < 4; ++kk) {
        int d0 = kk * 32 + kgrp * 8;
        f32x4 va = *(const f32x4*)(arow + d0);
        f32x4 vb = *(const f32x4*)(arow + d0 + 4);
        if (MODE == 1) {
            f32x4 s1 = *(const f32x4*)(coefs + d0);
            f32x4 s2 = *(const f32x4*)(coefs + d0 + 4);
            f32x4 t1 = *(const f32x4*)(coefs + 128 + d0);
            f32x4 t2 = *(const f32x4*)(coefs + 128 + d0 + 4);
#pragma unroll
            for (int j = 0; j < 4; ++j) {
                va[j] = fmaxf(va[j] * s1[j] + t1[j], 0.f);
                vb[j] = fmaxf(vb[j] * s2[j] + t2[j], 0.f);
            }
        }
        short8 afrag;
#pragma unroll
        for (int j = 0; j < 4; ++j) { afrag[j] = f2bf(va[j]); afrag[4 + j] = f2bf(vb[j]); }

        const short8* wf = (const short8*)Wfrag;
#pragma unroll
        for (int ct = 0; ct < 8; ++ct) {
            short8 wfr = wf[(ct * 4 + kk) * 64 + lane];
            acc[ct] = __builtin_amdgcn_mfma_f32_16x16x32_bf16(afrag, wfr, acc[ct], 0, 0, 0);
        }
    }

    // C/D layout: col = lane&15, row = (lane>>4)*4 + j
    int orow = r0 + kgrp * 4;
#pragma unroll
    for (int ct = 0; ct < 8; ++ct) {
        int col = ct * 16 + (lane & 15);
#pragma unroll
        for (int j = 0; j < 4; ++j) {
            int gr = orow + j;
            if (gr < NN)
                hout[(size_t)gr * DD + col] = (unsigned short)f2bf(acc[ct][j]);
        }
    }
}

// ---------------- CSR gather: agg[i] = dis[i]*sum(dis[s]*h[s]) + dis[i]^2*h[i]
// one wave per row; lane owns cols 2*lane, 2*lane+1
__global__ __launch_bounds__(256) void gather_k(const unsigned short* __restrict__ h,
                                                const int* __restrict__ ssrc,
                                                const float* __restrict__ ssdis,
                                                const int* __restrict__ rowptr,
                                                const float* __restrict__ dis,
                                                float* __restrict__ agg) {
    int wid  = (blockIdx.x * 256 + threadIdx.x) >> 6;
    int lane = threadIdx.x & 63;
    if (wid >= NN) return;
    int p0 = rowptr[wid], p1 = rowptr[wid + 1];
    const ushort2* hp = (const ushort2*)h;
    float ax = 0.f, ay = 0.f;
    for (int j = p0; j < p1; ++j) {
        int   s = ssrc[j];
        float w = ssdis[j];
        ushort2 hv = hp[(size_t)s * 64 + lane];
        ax += w * bf2f(hv.x);
        ay += w * bf2f(hv.y);
    }
    float d = dis[wid];
    ushort2 hs = hp[(size_t)wid * 64 + lane];
    float2 r;
    r.x = d * ax + d * d * bf2f(hs.x);
    r.y = d * ay + d * d * bf2f(hs.y);
    ((float2*)agg)[(size_t)wid * 64 + lane] = r;
}

// ---------------- BN stats: per-column sum & sumsq ----------------
__global__ __launch_bounds__(256) void bnstats_k(const float* __restrict__ x,
                                                 float* __restrict__ sums) {
    int c  = threadIdx.x & 127;
    int rg = threadIdx.x >> 7;
    float s = 0.f, s2 = 0.f;
    int stride = gridDim.x * 2;
    for (int r = blockIdx.x * 2 + rg; r < NN; r += stride) {
        float v = x[(size_t)r * DD + c];
        s += v; s2 += v * v;
    }
    __shared__ float ls[256], ls2[256];
    ls[threadIdx.x] = s; ls2[threadIdx.x] = s2;
    __syncthreads();
    if (rg == 0) {
        s  = ls[c]  + ls[c + 128];
        s2 = ls2[c] + ls2[c + 128];
        atomicAdd(&sums[c], s);
        atomicAdd(&sums[128 + c], s2);
    }
}

// ---------------- BN coefficients ----------------
__global__ void bncoef_k(const float* __restrict__ sums,
                         const float* __restrict__ gamma,
                         const float* __restrict__ beta,
                         float* __restrict__ coefs) {
    int c = threadIdx.x;
    if (c >= DD) return;
    const float n = (float)NN;
    float m  = sums[c] / n;
    float v  = sums[128 + c] / n - m * m;
    float is = rsqrtf(v + 1e-5f);
    float sc = gamma[c] * is;
    coefs[c] = sc;
    coefs[128 + c] = beta[c] - m * sc;
}

// ---------------- ratings: wave per pair, BN2+relu inline ----------------
__global__ __launch_bounds__(256) void ratings_k(const float* __restrict__ x,
                                                 const int* __restrict__ srcn,
                                                 const int* __restrict__ dstn,
                                                 const float* __restrict__ coefs,
                                                 float* __restrict__ out) {
    int wid  = (blockIdx.x * 256 + threadIdx.x) >> 6;
    int lane = threadIdx.x & 63;
    if (wid >= BB) return;
    int u = srcn[wid], v = dstn[wid];
    const float* xu = x + (size_t)u * DD;
    const float* xv = x + (size_t)v * DD;
    float acc = 0.f;
#pragma unroll
    for (int d0 = 0; d0 < DD; d0 += 64) {
        int d = d0 + lane;
        float sc = coefs[d], sh = coefs[128 + d];
        float a = fmaxf(xu[d] * sc + sh, 0.f);
        float b = fmaxf(xv[d] * sc + sh, 0.f);
        acc += a * b;
    }
#pragma unroll
    for (int off = 32; off; off >>= 1) acc += __shfl_down(acc, off, 64);
    if (lane == 0) out[wid] = acc;
}

extern "C" void kernel_launch(void* const* d_in, const int* in_sizes, int n_in,
                              void* d_out, int out_size, void* d_ws, size_t ws_size,
                              hipStream_t stream) {
    const int*   edge  = (const int*)d_in[0];      // [2,E]
    const int*   esrc  = edge;
    const int*   edst  = edge + EE;
    const int*   srcn  = (const int*)d_in[2];
    const int*   dstn  = (const int*)d_in[3];
    const float* uemb  = (const float*)d_in[4];
    const float* bemb  = (const float*)d_in[5];
    const float* W1    = (const float*)d_in[6];
    // b1 = d_in[7]  (per-column constant, cancels in BN)
    const float* g1    = (const float*)d_in[8];
    const float* be1   = (const float*)d_in[9];
    const float* W2    = (const float*)d_in[10];
    // b2 = d_in[11] (cancels in BN)
    const float* g2    = (const float*)d_in[12];
    const float* be2   = (const float*)d_in[13];
    float* out = (float*)d_out;

    // workspace layout (16B-aligned segments; NN padded to 150016)
    float*          agg    = (float*)d_ws;                               // N*D fp32
    unsigned short* hbuf   = (unsigned short*)(agg + (size_t)NN * DD);   // N*D bf16
    int*            cnt    = (int*)(hbuf + (size_t)NN * DD);             // 150016
    int*            rowptr = cnt + 150016;                               // 150016 (>= NN+1)
    int*            cur    = rowptr + 150016;                            // 150016
    float*          dis    = (float*)(cur + 150016);                     // 150016
    int*            ssrc   = (int*)(dis + 150016);                       // EE
    float*          ssdis  = (float*)(ssrc + EE);                        // EE
    short*          Wf1    = (short*)(ssdis + EE);                       // 16384 bf16
    short*          Wf2    = Wf1 + 16384;                                // 16384 bf16
    float*          sums   = (float*)(Wf2 + 16384);                      // 256
    float*          coef1  = sums + 256;                                 // 256
    float*          coef2  = coef1 + 256;                                // 256

    const int egrid = (EE + 255) / 256;            // 1954
    const int ggrid = (NN + 63) / 64;              // 2344 MFMA-GEMM blocks
    const int wgrid = (NN * 64) / 256;             // 37500 gather blocks (wave/row)

    // ---- CSR build + normalization + W fragments ----
    hipMemsetAsync(cnt, 0, 150016 * sizeof(int), stream);
    count_k<<<egrid, 256, 0, stream>>>(edst, cnt);
    scan1_k<<<NBLK, 256, 0, stream>>>(cnt, rowptr, cur /*bsum scratch tail*/ + 150016 - 1024);
    // NOTE: bsum needs its own space; reuse tail of `cur` BEFORE cur is written:
    // scan1 writes bsum into cur[150016-1024 .. ), scan2 scans it, scan3 consumes
    // it and then overwrites all of cur with cursor values. Safe: NBLK=586 block
    // sums live at cur[149?..] while scan3 writes cur[i] for i<NN=150000 — overlap!
    // -> use dedicated region instead: place bsum in sums-adjacent scratch? No:
    // simplest correct: bsum = ssrc (not yet filled at scan time).
    scan2_k<<<1, 1024, 0, stream>>>(cur + 150016 - 1024);
    scan3_k<<<NBLK, 256, 0, stream>>>(rowptr, cur + 150016 - 1024, cur);
    dis_k<<<NBLK, 256, 0, stream>>>(cnt, dis);
    fill_k<<<egrid, 256, 0, stream>>>(esrc, edst, dis, cur, ssrc, ssdis);
    wfrag_k<<<128, 256, 0, stream>>>(W1, W2, Wf1, Wf2);

    // ---- layer 1 ----
    gemm_mfma_k<0><<<ggrid, 256, 0, stream>>>(uemb, bemb, NUSERS, nullptr, Wf1, hbuf);
    gather_k<<<wgrid, 256, 0, stream>>>(hbuf, ssrc, ssdis, rowptr, dis, agg);
    hipMemsetAsync(sums, 0, 256 * sizeof(float), stream);
    bnstats_k<<<512, 256, 0, stream>>>(agg, sums);
    bncoef_k<<<1, 128, 0, stream>>>(sums, g1, be1, coef1);

    // ---- layer 2 (BN1+relu fused into GEMM A-load) ----
    gemm_mfma_k<1><<<ggrid, 256, 0, stream>>>(agg, nullptr, 0, coef1, Wf2, hbuf);
    gather_k<<<wgrid, 256, 0, stream>>>(hbuf, ssrc, ssdis, rowptr, dis, agg);
    hipMemsetAsync(sums, 0, 256 * sizeof(float), stream);
    bnstats_k<<<512, 256, 0, stream>>>(agg, sums);
    bncoef_k<<<1, 128, 0, stream>>>(sums, g2, be2, coef2);

    // ---- ratings (BN2+relu inline) ----
    ratings_k<<<BB / 4, 256, 0, stream>>>(agg, srcn, dstn, coef2, out);
}